// Round 4
// baseline (753.403 us; speedup 1.0000x reference)
//
#include <hip/hip_runtime.h>
#include <math.h>

#define N_NODES 50000
#define E1N 400000
#define E2N 100000
#define E_TOT 500000
#define ALPHAC 0.2f
#define DAMP 0.85f
#define EPSC 1e-12f

typedef __bf16 bf16_t;
typedef __bf16 bf16x4 __attribute__((ext_vector_type(4)));
typedef __bf16 bf16x8 __attribute__((ext_vector_type(8)));
typedef _Float16 f16_t;
typedef _Float16 f16x4 __attribute__((ext_vector_type(4)));
typedef float f32x4 __attribute__((ext_vector_type(4)));
typedef float f32x16 __attribute__((ext_vector_type(16)));

__device__ __forceinline__ float lrelu(float x) { return x > 0.f ? x : ALPHAC * x; }

// Pack [a1|a2] (K=128, N=256) into 32x32x16 B-fragment order for k_uv2.
__global__ __launch_bounds__(256) void k_pack12(const float* __restrict__ a,
                                                bf16_t* __restrict__ bp) {
  int i = blockIdx.x * 256 + threadIdx.x;  // 32768
  if (i >= 32768) return;
  int j = i & 7;
  int l = (i >> 3) & 63;
  int nt = (i >> 9) & 7;
  int ks = i >> 12;
  int c = nt * 32 + (l & 31);
  int o = (c < 128) ? c : c - 128;
  int koff = (c < 128) ? 0 : 128;
  int k = ks * 16 + ((l >> 5) << 3) + j;
  bp[i] = (bf16_t)a[o * 384 + koff + k];
}

// Pack a3 (K=128, N=128) B-fragments, 32x32x16 order (fallback path).
__global__ __launch_bounds__(256) void k_pack3(const float* __restrict__ a,
                                               bf16_t* __restrict__ bp) {
  int i = blockIdx.x * 256 + threadIdx.x;  // 16384
  if (i >= 16384) return;
  int j = i & 7;
  int l = (i >> 3) & 63;
  int nt = (i >> 9) & 3;
  int ks = i >> 11;
  int o = nt * 32 + (l & 31);
  int k = ks * 16 + ((l >> 5) << 3) + j;
  bp[i] = (bf16_t)a[o * 384 + 256 + k];
}

// Pack a3 (K=128, N=128) B-fragments, 16x16x32 order (passA4).
__global__ __launch_bounds__(256) void k_pack3c(const float* __restrict__ a,
                                                bf16_t* __restrict__ bp) {
  int i = blockIdx.x * 256 + threadIdx.x;  // 16384
  if (i >= 16384) return;
  int j = i & 7;
  int l = (i >> 3) & 63;
  int nt = (i >> 9) & 7;
  int ks = i >> 12;
  int o = nt * 16 + (l & 15);
  int k = ks * 32 + ((l >> 4) << 3) + j;
  bp[i] = (bf16_t)a[o * 384 + 256 + k];
}

// dst-degree count only (big path).
__global__ __launch_bounds__(256) void k_cnt(const int* __restrict__ edge,
                                             const int* __restrict__ nhop,
                                             int stride, int* __restrict__ cnt) {
  int e = blockIdx.x * 256 + threadIdx.x;
  if (e >= E_TOT) return;
  int d = (e < E1N) ? edge[(size_t)(E1N + e) * stride]
                    : nhop[(size_t)(E2N + (e - E1N)) * stride];
  atomicAdd(&cnt[d], 1);
}

// Fallback: edge split into sidx/didx (cnt unused).
__global__ __launch_bounds__(256) void k_edges(const int* __restrict__ edge,
                                               const int* __restrict__ nhop,
                                               int* __restrict__ sidx,
                                               int* __restrict__ didx, int stride) {
  int e = blockIdx.x * 256 + threadIdx.x;
  if (e >= E_TOT) return;
  int s, d;
  if (e < E1N) {
    s = edge[(size_t)e * stride];
    d = edge[(size_t)(E1N + e) * stride];
  } else {
    int t = e - E1N;
    s = nhop[(size_t)t * stride];
    d = nhop[(size_t)(E2N + t) * stride];
  }
  sidx[e] = s;
  didx[e] = d;
}

// Single-block exclusive scan of cnt[50000] -> csr_start, cursor.
__global__ __launch_bounds__(256) void k_scan(const int* __restrict__ cnt,
                                              int* __restrict__ csr_start,
                                              int* __restrict__ cursor) {
  __shared__ int ls[256];
  __shared__ int lofs[256];
  int t = threadIdx.x;
  int lo = t * 196, hi = lo + 196;
  if (hi > N_NODES) hi = N_NODES;
  int s = 0;
  for (int i = lo; i < hi; ++i) s += cnt[i];
  ls[t] = s;
  __syncthreads();
  if (t == 0) {
    int run = 0;
    for (int i = 0; i < 256; ++i) { lofs[i] = run; run += ls[i]; }
  }
  __syncthreads();
  int run = lofs[t];
  for (int i = lo; i < hi; ++i) {
    csr_start[i] = run;
    cursor[i] = run;
    run += cnt[i];
  }
}

// Sorted-CSR builder: epos[e] = slot, plus sorted sidx/didx.
__global__ __launch_bounds__(256) void k_pos2(const int* __restrict__ edge,
                                              const int* __restrict__ nhop,
                                              int stride, int* __restrict__ cursor,
                                              int* __restrict__ epos,
                                              int* __restrict__ sidx_s,
                                              int* __restrict__ didx_s) {
  int e = blockIdx.x * 256 + threadIdx.x;
  if (e >= E_TOT) return;
  int s, d;
  if (e < E1N) {
    s = edge[(size_t)e * stride];
    d = edge[(size_t)(E1N + e) * stride];
  } else {
    int t = e - E1N;
    s = nhop[(size_t)t * stride];
    d = nhop[(size_t)(E2N + t) * stride];
  }
  int pos = atomicAdd(&cursor[d], 1);
  epos[e] = pos;
  sidx_s[pos] = s;
  didx_s[pos] = d;
}

// UV = input @ [a1|a2].T -> bf16 [N_NODES][256]; column-half split grid.
__global__ __launch_bounds__(256) void k_uv2(const float* __restrict__ input,
                                             const bf16_t* __restrict__ bp12,
                                             bf16_t* __restrict__ uv) {
  const int tid = threadIdx.x, lane = tid & 63, wv = tid >> 6;
  const int blk = blockIdx.x >> 1, half = blockIdx.x & 1;
  const int ntoff = half * 4;
  const int n0 = blk * 128 + wv * 32;
  const int m = lane & 31, hi2 = lane >> 5;
  int n = n0 + m;
  if (n >= N_NODES) n = 0;
  const float* ar = input + (size_t)n * 128 + hi2 * 8;
  const bf16x8* bp = (const bf16x8*)bp12;

  f32x16 acc[4];
#pragma unroll
  for (int nt = 0; nt < 4; ++nt)
#pragma unroll
    for (int r = 0; r < 16; ++r) acc[nt][r] = 0.f;

#pragma unroll
  for (int ks = 0; ks < 8; ++ks) {
    float4 u0 = *(const float4*)(ar + ks * 16);
    float4 u1 = *(const float4*)(ar + ks * 16 + 4);
    bf16x8 af = {(bf16_t)u0.x, (bf16_t)u0.y, (bf16_t)u0.z, (bf16_t)u0.w,
                 (bf16_t)u1.x, (bf16_t)u1.y, (bf16_t)u1.z, (bf16_t)u1.w};
#pragma unroll
    for (int nt = 0; nt < 4; ++nt)
      acc[nt] = __builtin_amdgcn_mfma_f32_32x32x16_bf16(
          af, bp[(ks * 8 + ntoff + nt) * 64 + lane], acc[nt], 0, 0, 0);
  }
#pragma unroll
  for (int nt = 0; nt < 4; ++nt)
#pragma unroll
    for (int r = 0; r < 16; ++r) {
      int row = (r & 3) + ((r >> 2) << 3) + (hi2 << 2);
      int node = n0 + row;
      if (node < N_NODES)
        uv[(size_t)node * 256 + (ntoff + nt) * 32 + m] = (bf16_t)acc[nt][r];
    }
}

// Fused pass v4:
//  - A (64 emb rows) staged to LDS via registers (coalesced, swizzled)
//  - B (a3 fragments, 32KB) staged to LDS once per block (kills serialized L2 loads)
//  - u/v/epos prefetched at kernel start (latency absorbed by staging phase)
//  - P + edge_e scattered to CSR-sorted positions (consumer becomes streaming)
__global__ __launch_bounds__(256) void k_passA4(
    const float* __restrict__ eemb, const float* __restrict__ eembn,
    const bf16_t* __restrict__ uv, const int* __restrict__ edge,
    const int* __restrict__ nhop, int stride, const int* __restrict__ epos,
    const bf16_t* __restrict__ bp3c, const float* __restrict__ a2,
    float* __restrict__ edge_e_s, float* __restrict__ a_rowsum,
    bf16_t* __restrict__ P) {
  __shared__ __align__(16) char sA[16384];   // 64 rows x 256B (swizzled)
  __shared__ __align__(16) char sB[32768];   // a3 fragments, linear
  const int tid = threadIdx.x;
  const long long e0 = (long long)blockIdx.x * 64;
  const int lane = tid & 63;

  // ---- issue A-staging loads (streaming HBM) ----
  const int strow = tid >> 5;          // 0..7
  const int stcol = (tid & 31) * 4;    // float col
  float4 rg[8];
#pragma unroll
  for (int s = 0; s < 8; ++s) {
    int row = s * 8 + strow;
    long long e = e0 + row;
    rg[s] = make_float4(0.f, 0.f, 0.f, 0.f);
    if (e < E_TOT) {
      const float* src = (e < E1N) ? eemb + (size_t)e * 128
                                   : eembn + (size_t)(e - E1N) * 128;
      rg[s] = *(const float4*)(src + stcol);
    }
  }
  // ---- issue B-staging loads (32768B linear, L2-resident) ----
  int4 rb[8];
  {
    const int4* bsrc = (const int4*)bp3c;
#pragma unroll
    for (int i = 0; i < 8; ++i) rb[i] = bsrc[i * 256 + tid];
  }
  // ---- issue s/d/pos loads (broadcast within 32-lane group) ----
  const int g = tid >> 5;   // epilogue group 0..7
  const int ml = tid & 31;
  int sarr[8], darr[8], parr[8];
#pragma unroll
  for (int i = 0; i < 8; ++i) {
    long long e = e0 + i * 8 + g;
    sarr[i] = 0; darr[i] = 0; parr[i] = 0;
    if (e < E_TOT) {
      if (e < E1N) {
        sarr[i] = edge[(size_t)e * stride];
        darr[i] = edge[(size_t)(E1N + e) * stride];
      } else {
        long long t = e - E1N;
        sarr[i] = nhop[(size_t)t * stride];
        darr[i] = nhop[(size_t)(E2N + t) * stride];
      }
      parr[i] = epos[e];
    }
  }
  // ---- write A to LDS (waits only on rg) ----
#pragma unroll
  for (int s = 0; s < 8; ++s) {
    int row = s * 8 + strow;
    bf16x4 b = {(bf16_t)rg[s].x, (bf16_t)rg[s].y, (bf16_t)rg[s].z, (bf16_t)rg[s].w};
    *(bf16x4*)(sA + row * 256 + ((stcol * 2) ^ ((row & 7) << 4))) = b;
  }
  // ---- write B to LDS ----
  {
    int4* bdst = (int4*)sB;
#pragma unroll
    for (int i = 0; i < 8; ++i) bdst[i * 256 + tid] = rb[i];
  }
  // ---- issue u/v prefetch (random L2/L3 gathers; in flight over staging) ----
  const int cl = ml * 4;
  bf16x4 uu[8], vv[8];
#pragma unroll
  for (int i = 0; i < 8; ++i) {
    uu[i] = *(const bf16x4*)(uv + (size_t)sarr[i] * 256 + cl);
    vv[i] = *(const bf16x4*)(uv + (size_t)darr[i] * 256 + 128 + cl);
  }
  __syncthreads();

  // ---- phase 2: GEMM from LDS only ----
  const int wv = tid >> 6;
  const int cc = lane & 15, kg = lane >> 4;
  const int arow = wv * 16 + cc;
  const int swz = (arow & 7) << 4;
  const bf16x8* sBv = (const bf16x8*)sB;

  f32x4 acc[8];
#pragma unroll
  for (int nt = 0; nt < 8; ++nt) acc[nt] = (f32x4){0.f, 0.f, 0.f, 0.f};

#pragma unroll
  for (int ks = 0; ks < 4; ++ks) {
    bf16x8 af = *(const bf16x8*)(sA + arow * 256 + ((ks * 64 + kg * 16) ^ swz));
#pragma unroll
    for (int nt = 0; nt < 8; ++nt)
      acc[nt] = __builtin_amdgcn_mfma_f32_16x16x32_bf16(
          af, sBv[(ks * 8 + nt) * 64 + lane], acc[nt], 0, 0, 0);
  }
  __syncthreads();

  // ---- phase 3: C -> fp16 into sA ----
#pragma unroll
  for (int nt = 0; nt < 8; ++nt)
#pragma unroll
    for (int r = 0; r < 4; ++r) {
      int row = wv * 16 + kg * 4 + r;
      int cb = (nt * 16 + cc) * 2;
      *(f16_t*)(sA + row * 256 + (cb ^ ((row & 7) << 4))) = (f16_t)acc[nt][r];
    }
  __syncthreads();

  // ---- phase 4: pure-compute epilogue, scatter to sorted positions ----
  {
    const float4 a2v = *(const float4*)(a2 + cl);
#pragma unroll
    for (int i = 0; i < 8; ++i) {
      int row = i * 8 + g;
      long long e = e0 + row;
      if (e < E_TOT) {
        f16x4 cc4 = *(const f16x4*)(sA + row * 256 + ((cl * 2) ^ ((row & 7) << 4)));
        float p0 = lrelu((float)cc4[0] + (float)uu[i][0] + (float)vv[i][0]);
        float p1 = lrelu((float)cc4[1] + (float)uu[i][1] + (float)vv[i][1]);
        float p2 = lrelu((float)cc4[2] + (float)uu[i][2] + (float)vv[i][2]);
        float p3 = lrelu((float)cc4[3] + (float)uu[i][3] + (float)vv[i][3]);
        bf16x4 po = {(bf16_t)p0, (bf16_t)p1, (bf16_t)p2, (bf16_t)p3};
        *(bf16x4*)(P + (size_t)parr[i] * 128 + cl) = po;
        float sac = p0 * a2v.x + p1 * a2v.y + p2 * a2v.z + p3 * a2v.w;
#pragma unroll
        for (int off = 1; off < 32; off <<= 1) sac += __shfl_xor(sac, off, 64);
        if (ml == 0) {
          float ev = expf(-lrelu(sac));
          edge_e_s[parr[i]] = ev;
          atomicAdd(&a_rowsum[darr[i]], ev);
        }
      }
    }
  }
}

// h_prime over sorted CSR: P reads fully sequential; depth-1 pipeline.
__global__ __launch_bounds__(256) void k_hprime_s(
    const bf16_t* __restrict__ P, const int* __restrict__ csr_start,
    const int* __restrict__ cnt, const float* __restrict__ rel_att_s,
    const int* __restrict__ sidx_s, const float* __restrict__ new_rank,
    float* __restrict__ out) {
  int gnode = (blockIdx.x << 3) | (threadIdx.x >> 5);
  if (gnode >= N_NODES) return;
  int m = threadIdx.x & 31;
  int start = csr_start[gnode], deg = cnt[gnode];
  float a0 = 0.f, a1 = 0.f, a2v = 0.f, a3v = 0.f;
  if (deg > 0) {
    float rel_c = rel_att_s[start];
    float rk_c = new_rank[sidx_s[start]];
    bf16x4 p_c = *(const bf16x4*)(P + (size_t)start * 128 + m * 4);
    for (int i = 0; i < deg; ++i) {
      int qn = start + ((i + 1 < deg) ? i + 1 : i);
      float rel_n = rel_att_s[qn];
      float rk_n = new_rank[sidx_s[qn]];
      bf16x4 p_n = *(const bf16x4*)(P + (size_t)qn * 128 + m * 4);
      float we = rel_c * rk_c;
      a0 += we * (float)p_c[0];
      a1 += we * (float)p_c[1];
      a2v += we * (float)p_c[2];
      a3v += we * (float)p_c[3];
      rel_c = rel_n; rk_c = rk_n; p_c = p_n;
    }
  }
  float4 r;
  r.x = a0 > 0.f ? a0 : expm1f(a0);
  r.y = a1 > 0.f ? a1 : expm1f(a1);
  r.z = a2v > 0.f ? a2v : expm1f(a2v);
  r.w = a3v > 0.f ? a3v : expm1f(a3v);
  *(float4*)(out + (size_t)gnode * 128 + m * 4) = r;
}

// ---------- fallback recompute-ACCUM pass ----------
template <bool ACCUM>
__global__ __launch_bounds__(256, 3) void k_pass(
    const float* __restrict__ eemb, const float* __restrict__ eembn,
    const bf16_t* __restrict__ uv, const int* __restrict__ sidx,
    const int* __restrict__ didx, const bf16_t* __restrict__ bp3,
    const float* __restrict__ a2, float* __restrict__ edge_e,
    float* __restrict__ a_rowsum, const float* __restrict__ rel_att,
    const float* __restrict__ new_rank, float* __restrict__ hout) {
  __shared__ bf16_t s_sum[128][136];
  const int tid = threadIdx.x;
  const long long e0 = (long long)blockIdx.x * 128;
  {
    const int g = tid >> 5;
    const int cl = (tid & 31) * 4;
#pragma unroll
    for (int i = 0; i < 16; ++i) {
      int el = i * 8 + g;
      long long e = e0 + el;
      float sx = 0.f, sy = 0.f, sz = 0.f, sw = 0.f;
      if (e < E_TOT) {
        int s = sidx[e], d = didx[e];
        bf16x4 u = *(const bf16x4*)(uv + (size_t)s * 256 + cl);
        bf16x4 v = *(const bf16x4*)(uv + (size_t)d * 256 + 128 + cl);
        sx = (float)u[0] + (float)v[0];
        sy = (float)u[1] + (float)v[1];
        sz = (float)u[2] + (float)v[2];
        sw = (float)u[3] + (float)v[3];
      }
      bf16x4 o = {(bf16_t)sx, (bf16_t)sy, (bf16_t)sz, (bf16_t)sw};
      *(bf16x4*)&s_sum[el][cl] = o;
    }
  }
  __syncthreads();

  const int lane = tid & 63;
  const int wv = tid >> 6;
  const long long e0w = e0 + wv * 32;
  if (e0w >= E_TOT) return;
  const int m = lane & 31, hi2 = lane >> 5;
  const long long e = e0w + m;
  const float* b2 = (e < E1N) ? (eemb + (size_t)e * 128)
                              : (eembn + (size_t)(e - E1N) * 128);
  const float* ar = b2 + hi2 * 8;

  const bf16x8* bp = (const bf16x8*)bp3;
  f32x16 acc[4];
#pragma unroll
  for (int nt = 0; nt < 4; ++nt)
#pragma unroll
    for (int r = 0; r < 16; ++r) acc[nt][r] = 0.f;

  auto loadA = [&](int ks) -> bf16x8 {
    float4 u0 = *(const float4*)(ar + ks * 16);
    float4 u1 = *(const float4*)(ar + ks * 16 + 4);
    bf16x8 rr = {(bf16_t)u0.x, (bf16_t)u0.y, (bf16_t)u0.z, (bf16_t)u0.w,
                 (bf16_t)u1.x, (bf16_t)u1.y, (bf16_t)u1.z, (bf16_t)u1.w};
    return rr;
  };

  bf16x8 a_cur = loadA(0);
  bf16x8 bb[4], bn[4];
#pragma unroll
  for (int nt = 0; nt < 4; ++nt) bb[nt] = bp[nt * 64 + lane];

#pragma unroll
  for (int ks = 0; ks < 8; ++ks) {
    bf16x8 a_nxt;
    if (ks < 7) {
      a_nxt = loadA(ks + 1);
#pragma unroll
      for (int nt = 0; nt < 4; ++nt) bn[nt] = bp[((ks + 1) * 4 + nt) * 64 + lane];
    }
#pragma unroll
    for (int nt = 0; nt < 4; ++nt)
      acc[nt] = __builtin_amdgcn_mfma_f32_32x32x16_bf16(a_cur, bb[nt], acc[nt], 0, 0, 0);
    a_cur = a_nxt;
#pragma unroll
    for (int nt = 0; nt < 4; ++nt) bb[nt] = bn[nt];
  }

  if (!ACCUM) {
    float sac[16];
#pragma unroll
    for (int r = 0; r < 16; ++r) sac[r] = 0.f;
#pragma unroll
    for (int nt = 0; nt < 4; ++nt) {
      float a2v = a2[nt * 32 + m];
      int o = nt * 32 + m;
#pragma unroll
      for (int r = 0; r < 16; ++r) {
        int row = (r & 3) + ((r >> 2) << 3) + (hi2 << 2);
        float c = acc[nt][r] + (float)s_sum[wv * 32 + row][o];
        sac[r] += lrelu(c) * a2v;
      }
    }
#pragma unroll
    for (int off = 1; off < 32; off <<= 1) {
#pragma unroll
      for (int r = 0; r < 16; ++r) sac[r] += __shfl_xor(sac[r], off, 64);
    }
    if (m == 0) {
#pragma unroll
      for (int r = 0; r < 16; ++r) {
        int row = (r & 3) + ((r >> 2) << 3) + (hi2 << 2);
        long long ee_i = e0w + row;
        float ev = expf(-lrelu(sac[r]));
        edge_e[ee_i] = ev;
        atomicAdd(&a_rowsum[didx[ee_i]], ev);
      }
    }
  } else {
    float w_m = rel_att[e] * new_rank[sidx[e]];
    int d = didx[e];
    float wr[16];
    int dr[16];
#pragma unroll
    for (int r = 0; r < 16; ++r) {
      int row = (r & 3) + ((r >> 2) << 3) + (hi2 << 2);
      wr[r] = __shfl(w_m, row, 64);
      dr[r] = __shfl(d, row, 64);
    }
#pragma unroll
    for (int nt = 0; nt < 4; ++nt) {
      int o = nt * 32 + m;
#pragma unroll
      for (int r = 0; r < 16; ++r) {
        int row = (r & 3) + ((r >> 2) << 3) + (hi2 << 2);
        float c = acc[nt][r] + (float)s_sum[wv * 32 + row][o];
        atomicAdd(&hout[(size_t)dr[r] * 128 + o], lrelu(c) * wr[r]);
      }
    }
  }
}

// rel_att = edge_e / a_rowsum[d]; e_rowsum[src] += rel_att. (works in-place)
__global__ __launch_bounds__(256) void k_relatt(const float* __restrict__ edge_e,
                                                const int* __restrict__ didx,
                                                const int* __restrict__ sidx,
                                                const float* __restrict__ a_rowsum,
                                                float* __restrict__ rel_att,
                                                float* __restrict__ e_rowsum) {
  int e = blockIdx.x * 256 + threadIdx.x;
  if (e >= E_TOT) return;
  float rs = a_rowsum[didx[e]];
  rs = (rs == 0.f) ? EPSC : rs;
  float r = edge_e[e] / rs;
  rel_att[e] = r;
  atomicAdd(&e_rowsum[sidx[e]], r);
}

__global__ __launch_bounds__(256) void k_val(const float* __restrict__ rel_att,
                                             const int* __restrict__ sidx,
                                             const int* __restrict__ didx,
                                             const float* __restrict__ rank,
                                             const float* __restrict__ e_rowsum,
                                             float* __restrict__ e_colsum) {
  int e = blockIdx.x * 256 + threadIdx.x;
  if (e >= E_TOT) return;
  int s = sidx[e];
  float er = e_rowsum[s];
  er = (er == 0.f) ? EPSC : er;
  float val = rel_att[e] * rank[s] / er;
  atomicAdd(&e_colsum[didx[e]], val);
}

__global__ __launch_bounds__(256) void k_rank(const float* __restrict__ e_colsum,
                                              float* __restrict__ new_rank,
                                              float* __restrict__ out_tail) {
  int n = blockIdx.x * 256 + threadIdx.x;
  if (n >= N_NODES) return;
  float nr = 1.f - DAMP + DAMP * e_colsum[n];
  new_rank[n] = nr;
  out_tail[n] = nr;
}

__global__ __launch_bounds__(256) void k_elu(float* __restrict__ h) {
  int i = blockIdx.x * 256 + threadIdx.x;
  if (i < N_NODES * 128) {
    float x = h[i];
    h[i] = x > 0.f ? x : expm1f(x);
  }
}

extern "C" void kernel_launch(void* const* d_in, const int* in_sizes, int n_in,
                              void* d_out, int out_size, void* d_ws, size_t ws_size,
                              hipStream_t stream) {
  const float* input = (const float*)d_in[0];
  const int* edge = (const int*)d_in[1];
  const float* eemb = (const float*)d_in[2];
  const int* enh = (const int*)d_in[3];
  const float* eembn = (const float*)d_in[4];
  const float* rank = (const float*)d_in[5];
  const float* a = (const float*)d_in[6];
  const float* a2 = (const float*)d_in[7];
  float* out = (float*)d_out;

  int estride = (in_sizes[1] == 2 * E1N) ? 1 : 2;

  char* ws = (char*)d_ws;
  bf16_t* bp12 = (bf16_t*)(ws);                 //     65,536
  bf16_t* bp3s = (bf16_t*)(ws + 65536);         //     32,768 (shared pack slot)
  bf16_t* uv = (bf16_t*)(ws + 98304);           // 25,600,000 -> 25,698,304
  int* epos = (int*)(ws + 25698304);            //  2,000,000 (fb: sidx)
  int* sidx_s = (int*)(ws + 27698304);          //  2,000,000 (fb: didx)
  int* didx_s = (int*)(ws + 29698304);          //  2,000,000 (fb: rel_att)
  float* edge_e_s = (float*)(ws + 31698304);    //  2,000,000 (fb: edge_e)
  int* csr_start = (int*)(ws + 33698304);       //    200,000
  int* cursor = (int*)(ws + 33898304);          //    200,000
  int* cnt = (int*)(ws + 34098304);             //    200,000
  float* a_rowsum = (float*)(ws + 34298304);    //    200,000
  float* e_rowsum = (float*)(ws + 34498304);    //    200,000
  float* e_colsum = (float*)(ws + 34698304);    //    200,000
  float* new_rank = (float*)(ws + 34898304);    //    200,000
  bf16_t* P = (bf16_t*)(ws + 35098624);         // 128,000,000 (512B aligned)
                                                // end: 163,098,624

  const bool big = ws_size >= 163098624ULL;

  const int NB = (E_TOT + 127) / 128;
  const int NB4 = (E_TOT + 63) / 64;
  const int EB = (E_TOT + 255) / 256;
  const int UVB = 2 * ((N_NODES + 127) / 128);

  if (big) {
    // zero cnt + a_rowsum + e_rowsum + e_colsum (contiguous)
    hipMemsetAsync(cnt, 0, 4 * 200000, stream);

    k_pack12<<<128, 256, 0, stream>>>(a, bp12);
    k_pack3c<<<64, 256, 0, stream>>>(a, bp3s);
    k_cnt<<<EB, 256, 0, stream>>>(edge, enh, estride, cnt);
    k_scan<<<1, 256, 0, stream>>>(cnt, csr_start, cursor);
    k_pos2<<<EB, 256, 0, stream>>>(edge, enh, estride, cursor, epos, sidx_s, didx_s);
    k_uv2<<<UVB, 256, 0, stream>>>(input, bp12, uv);

    k_passA4<<<NB4, 256, 0, stream>>>(eemb, eembn, uv, edge, enh, estride, epos,
                                      bp3s, a2, edge_e_s, a_rowsum, P);
    // sorted-domain normalization chain (rel_att in-place over edge_e_s)
    k_relatt<<<EB, 256, 0, stream>>>(edge_e_s, didx_s, sidx_s, a_rowsum,
                                     edge_e_s, e_rowsum);
    k_val<<<EB, 256, 0, stream>>>(edge_e_s, sidx_s, didx_s, rank, e_rowsum, e_colsum);
    k_rank<<<(N_NODES + 255) / 256, 256, 0, stream>>>(e_colsum, new_rank,
                                                      out + (size_t)N_NODES * 128);
    k_hprime_s<<<(N_NODES + 7) / 8, 256, 0, stream>>>(P, csr_start, cnt, edge_e_s,
                                                      sidx_s, new_rank, out);
  } else {
    // fallback: two-pass recompute + atomic hout (unsorted domain, slot reuse)
    int* sidx_fb = epos;
    int* didx_fb = sidx_s;
    float* rel_fb = (float*)didx_s;
    float* ee_fb = edge_e_s;

    hipMemsetAsync(cnt, 0, 4 * 200000, stream);
    hipMemsetAsync(out, 0, (size_t)N_NODES * 128 * 4, stream);

    k_pack12<<<128, 256, 0, stream>>>(a, bp12);
    k_pack3<<<64, 256, 0, stream>>>(a, bp3s);
    k_edges<<<EB, 256, 0, stream>>>(edge, enh, sidx_fb, didx_fb, estride);
    k_uv2<<<UVB, 256, 0, stream>>>(input, bp12, uv);

    k_pass<false><<<NB, 256, 0, stream>>>(eemb, eembn, uv, sidx_fb, didx_fb, bp3s,
                                          a2, ee_fb, a_rowsum, nullptr, nullptr,
                                          nullptr);
    k_relatt<<<EB, 256, 0, stream>>>(ee_fb, didx_fb, sidx_fb, a_rowsum, rel_fb,
                                     e_rowsum);
    k_val<<<EB, 256, 0, stream>>>(rel_fb, sidx_fb, didx_fb, rank, e_rowsum, e_colsum);
    k_rank<<<(N_NODES + 255) / 256, 256, 0, stream>>>(e_colsum, new_rank,
                                                      out + (size_t)N_NODES * 128);
    k_pass<true><<<NB, 256, 0, stream>>>(eemb, eembn, uv, sidx_fb, didx_fb, bp3s,
                                         a2, nullptr, nullptr, rel_fb, new_rank, out);
    k_elu<<<(N_NODES * 128 + 255) / 256, 256, 0, stream>>>(out);
  }
}